// Round 8
// baseline (452.881 us; speedup 1.0000x reference)
//
#include <hip/hip_runtime.h>
#include <hip/hip_fp16.h>

#define N_NODES 100000
#define N_EDGES 1000000
#define N_GRAPHS 1000
#define EMBED 64
#define OUT_DIM 128
#define BN_EPS 1e-5f
#define NBINS 782                          // dst>>7 -> 128 nodes per bin
#define NSCB 512                           // scatter blocks (fixed edge ranges)
#define EPB ((N_EDGES + NSCB - 1) / NSCB)  // 1954 edges per block
#define NTILES (N_NODES / 16)              // 6250 exact

#define GB_BLOCKS 512
#define GB_WAVES (GB_BLOCKS * 4)           // 2048 waves
#define TPW 4                              // ceil(6250/2048) tiles per wave
#define GRAM_BLOCKS 64
#define NCHUNKS (N_NODES / 32)             // 3125 exact

typedef _Float16 half8 __attribute__((ext_vector_type(8)));
typedef float floatx4 __attribute__((ext_vector_type(4)));

// R7 verdict: grid-barrier cost (~19us each, mechanism-resistant: v2/v3/v4 all tried)
// is structural. This version ELIMINATES grid barriers: BN stats are computed
// analytically from m = sum_v t_v and S = sum_v t_v t_v^T (Gram), since
// h_pre = t@W+b gives colsum = m@W + N b and colsq_j = (W^T S W)_jj + 2 b_j (m@W)_j + N b_j^2.
// Pipeline per layer: gather -> gram -> stats(tiny) -> gemm+bn one-pass (no sync).

// ---------------- one-time structure kernels ----------------

__global__ void embed_kernel(const int* __restrict__ nfeat,
                             const float* __restrict__ atom_embed,
                             float4* __restrict__ h4,
                             __half* __restrict__ hh,
                             const int* __restrict__ gid,
                             int* __restrict__ gstart,
                             float* __restrict__ gsum) {
    int idx = blockIdx.x * blockDim.x + threadIdx.x;   // one float4 each
    if (idx <= N_NODES) {   // folded gbound
        int cur  = (idx < N_NODES) ? gid[idx] : N_GRAPHS;
        int prev = (idx == 0) ? -1 : gid[idx - 1];
        for (int g = prev + 1; g <= cur; ++g) gstart[g] = idx;
    }
    if (idx < N_GRAPHS * EMBED) gsum[idx] = 0.0f;
    if (idx >= N_NODES * 16) return;
    int v = idx >> 4, q = idx & 15;
    const float4* ae = (const float4*)atom_embed;
    float4 val = ae[nfeat[v] * 16 + q];
    h4[idx] = val;
    __half2 m0 = __floats2half2_rn(val.x, val.y);
    __half2 m1 = __floats2half2_rn(val.z, val.w);
    uint2 packed;
    packed.x = *(unsigned*)&m0;
    packed.y = *(unsigned*)&m1;
    ((uint2*)hh)[idx] = packed;
}

__global__ void hist2_kernel(const int* __restrict__ dst, int* __restrict__ blockhist) {
    __shared__ int hist[NBINS];
    for (int i = threadIdx.x; i < NBINS; i += 256) hist[i] = 0;
    __syncthreads();
    int b = blockIdx.x;
    int e0 = b * EPB, e1 = min(e0 + EPB, N_EDGES);
    for (int e = e0 + threadIdx.x; e < e1; e += 256)
        atomicAdd(&hist[dst[e] >> 7], 1);
    __syncthreads();
    for (int i = threadIdx.x; i < NBINS; i += 256)
        blockhist[i * NSCB + b] = hist[i];
}

__global__ void binreduce_kernel(const int* __restrict__ blockhist,
                                 int* __restrict__ gofs, int* __restrict__ total) {
    __shared__ int sm[NSCB];
    int bin = blockIdx.x;
    int i = threadIdx.x;   // 0..511
    int orig = blockhist[bin * NSCB + i];
    sm[i] = orig;
    __syncthreads();
    for (int off = 1; off < NSCB; off <<= 1) {
        int val = sm[i];
        if (i >= off) val += sm[i - off];
        __syncthreads();
        sm[i] = val;
        __syncthreads();
    }
    gofs[bin * NSCB + i] = sm[i] - orig;   // exclusive within bin
    if (i == NSCB - 1) total[bin] = sm[i];
}

// scan bin totals -> binoff; zero S/m accumulators; pack W frags
__global__ void binscan_kernel(const int* __restrict__ total,
                               int* __restrict__ binoff, float* __restrict__ zbuf,
                               const float* __restrict__ conv_W,
                               _Float16* __restrict__ wfrag) {
    __shared__ int sm[1024];
    int i = threadIdx.x;
    for (int s = i; s < 3 * 4096 + 3 * 64; s += 1024) zbuf[s] = 0.0f;  // Sbuf + mbuf
    // folded wpack: 3 layers x 512 slots
    for (int s = i; s < 3 * 512; s += 1024) {
        int L = s >> 9, slot = s & 511;
        int lane = slot & 63;
        int f = slot >> 6;          // nt*2+kh
        int nt = f >> 1, kh = f & 1;
        int n  = nt * 16 + (lane & 15);
        int k0 = kh * 32 + (lane >> 4) * 8;
        const float* W = conv_W + L * 4096;
        _Float16* out = wfrag + L * 4096;
#pragma unroll
        for (int j = 0; j < 8; ++j)
            out[slot * 8 + j] = (_Float16)W[(k0 + j) * 64 + n];
    }
    int orig = (i < NBINS) ? total[i] : 0;
    sm[i] = orig;
    __syncthreads();
    for (int off = 1; off < 1024; off <<= 1) {
        int val = sm[i];
        if (i >= off) val += sm[i - off];
        __syncthreads();
        sm[i] = val;
        __syncthreads();
    }
    if (i < NBINS) binoff[i] = sm[i] - orig;
    if (i == 0) binoff[NBINS] = N_EDGES;
}

__global__ void binscatter_kernel(const int* __restrict__ src, const int* __restrict__ dst,
                                  const int* __restrict__ efeat,
                                  const int* __restrict__ binoff, const int* __restrict__ gofs,
                                  unsigned* __restrict__ binned) {
    __shared__ int cur[NBINS];
    int b = blockIdx.x;
    for (int i = threadIdx.x; i < NBINS; i += 256)
        cur[i] = binoff[i] + gofs[i * NSCB + b];
    __syncthreads();
    int e0 = b * EPB, e1 = min(e0 + EPB, N_EDGES);
    for (int e = e0 + threadIdx.x; e < e1; e += 256) {
        int t = dst[e];
        int bin = t >> 7;
        int pos = atomicAdd(&cur[bin], 1);   // LDS atomic
        binned[pos] = (unsigned)src[e] | ((unsigned)efeat[e] << 17)
                    | ((unsigned)(t & 127) << 20);
    }
}

__global__ void bincsr_kernel(const unsigned* __restrict__ binned,
                              const int* __restrict__ binoff,
                              int* __restrict__ rowptr,
                              unsigned* __restrict__ ebuf) {
    __shared__ int cnt[128];
    __shared__ int sc[128];
    int b = blockIdx.x;
    int tid = threadIdx.x;
    int base = binoff[b], end = binoff[b + 1];

    if (tid < 128) cnt[tid] = 0;
    __syncthreads();

    for (int i = base + tid; i < end; i += 256)
        atomicAdd(&cnt[binned[i] >> 20], 1);
    __syncthreads();

    if (tid < 128) sc[tid] = cnt[tid];
    __syncthreads();
    for (int off = 1; off < 128; off <<= 1) {
        int val = 0;
        if (tid < 128) {
            val = sc[tid];
            if (tid >= off) val += sc[tid - off];
        }
        __syncthreads();
        if (tid < 128) sc[tid] = val;
        __syncthreads();
    }
    if (tid < 128) {
        int excl = sc[tid] - cnt[tid];
        int v = b * 128 + tid;
        if (v < N_NODES) rowptr[v] = base + excl;
        cnt[tid] = excl;   // becomes running cursor
    }
    if (b == 0 && tid == 255) rowptr[N_NODES] = N_EDGES;
    __syncthreads();

    for (int i = base + tid; i < end; i += 256) {
        unsigned rec = binned[i];
        int dl = rec >> 20;
        int pos = base + atomicAdd(&cnt[dl], 1);
        ebuf[pos] = (rec & 0x1FFFFu) | (((rec >> 17) & 0x7u) << 20);
    }
}

// ---------------- per-layer kernels ----------------

// Gather: quarter-wave per node. At the random-line service-rate wall (R6/R10/R18).
__launch_bounds__(256, 6)
__global__ void gather_kernel(const int* __restrict__ rowptr,
                              const unsigned* __restrict__ ebuf,
                              const float* __restrict__ bond,    // [5,64]
                              const __half* __restrict__ hh,     // fp16 mirror
                              const float* __restrict__ hmast,   // fp32 master
                              __half* __restrict__ t16) {
    __shared__ float bond_s[5 * EMBED];
    for (int i = threadIdx.x; i < 5 * EMBED; i += 256) bond_s[i] = bond[i];
    __syncthreads();

    int sl = threadIdx.x & 15;    // uint2 slot: dims 4sl..4sl+3
    int d0 = sl * 4;
    int gq = (blockIdx.x * 256 + threadIdx.x) >> 4;   // global quarter id
    int nq = (gridDim.x * 256) >> 4;
    const uint2* hhq = (const uint2*)hh;    // 16 uint2 per node row

    for (int v = gq; v < N_NODES; v += nq) {
        int rb = rowptr[v], re = rowptr[v + 1];
        float4 a0 = {0,0,0,0}, a1 = {0,0,0,0}, a2 = {0,0,0,0}, a3 = {0,0,0,0};
        int e = rb;
        for (; e + 4 <= re; e += 4) {
            unsigned p0 = ebuf[e + 0];
            unsigned p1 = ebuf[e + 1];
            unsigned p2 = ebuf[e + 2];
            unsigned p3 = ebuf[e + 3];
            uint2 g0 = hhq[(size_t)(p0 & 0xFFFFFu) * 16 + sl];
            uint2 g1 = hhq[(size_t)(p1 & 0xFFFFFu) * 16 + sl];
            uint2 g2 = hhq[(size_t)(p2 & 0xFFFFFu) * 16 + sl];
            uint2 g3 = hhq[(size_t)(p3 & 0xFFFFFu) * 16 + sl];
            const float* c0 = &bond_s[(p0 >> 20) * EMBED + d0];
            const float* c1 = &bond_s[(p1 >> 20) * EMBED + d0];
            const float* c2 = &bond_s[(p2 >> 20) * EMBED + d0];
            const float* c3 = &bond_s[(p3 >> 20) * EMBED + d0];
            float2 f0a = __half22float2(*(const __half2*)&g0.x);
            float2 f0b = __half22float2(*(const __half2*)&g0.y);
            float2 f1a = __half22float2(*(const __half2*)&g1.x);
            float2 f1b = __half22float2(*(const __half2*)&g1.y);
            float2 f2a = __half22float2(*(const __half2*)&g2.x);
            float2 f2b = __half22float2(*(const __half2*)&g2.y);
            float2 f3a = __half22float2(*(const __half2*)&g3.x);
            float2 f3b = __half22float2(*(const __half2*)&g3.y);
            a0.x += fmaxf(f0a.x + c0[0], 0.f); a0.y += fmaxf(f0a.y + c0[1], 0.f);
            a0.z += fmaxf(f0b.x + c0[2], 0.f); a0.w += fmaxf(f0b.y + c0[3], 0.f);
            a1.x += fmaxf(f1a.x + c1[0], 0.f); a1.y += fmaxf(f1a.y + c1[1], 0.f);
            a1.z += fmaxf(f1b.x + c1[2], 0.f); a1.w += fmaxf(f1b.y + c1[3], 0.f);
            a2.x += fmaxf(f2a.x + c2[0], 0.f); a2.y += fmaxf(f2a.y + c2[1], 0.f);
            a2.z += fmaxf(f2b.x + c2[2], 0.f); a2.w += fmaxf(f2b.y + c2[3], 0.f);
            a3.x += fmaxf(f3a.x + c3[0], 0.f); a3.y += fmaxf(f3a.y + c3[1], 0.f);
            a3.z += fmaxf(f3b.x + c3[2], 0.f); a3.w += fmaxf(f3b.y + c3[3], 0.f);
        }
        for (; e < re; ++e) {
            unsigned p = ebuf[e];
            uint2 g = hhq[(size_t)(p & 0xFFFFFu) * 16 + sl];
            const float* c = &bond_s[(p >> 20) * EMBED + d0];
            float2 fa = __half22float2(*(const __half2*)&g.x);
            float2 fb = __half22float2(*(const __half2*)&g.y);
            a0.x += fmaxf(fa.x + c[0], 0.f); a0.y += fmaxf(fa.y + c[1], 0.f);
            a0.z += fmaxf(fb.x + c[2], 0.f); a0.w += fmaxf(fb.y + c[3], 0.f);
        }
        float inv = 1.0f / fmaxf((float)(re - rb), 1.0f);
        float4 hr = ((const float4*)hmast)[(size_t)v * 16 + sl];
        float tx = (a0.x + a1.x + a2.x + a3.x) * inv + hr.x;
        float ty = (a0.y + a1.y + a2.y + a3.y) * inv + hr.y;
        float tz = (a0.z + a1.z + a2.z + a3.z) * inv + hr.z;
        float tw = (a0.w + a1.w + a2.w + a3.w) * inv + hr.w;
        __half2 m0 = __floats2half2_rn(tx, ty);
        __half2 m1 = __floats2half2_rn(tz, tw);
        uint2 packed;
        packed.x = *(unsigned*)&m0;
        packed.y = *(unsigned*)&m1;
        ((uint2*)t16)[(size_t)v * 16 + sl] = packed;
    }
}

// Gram: S = sum_v t_v t_v^T (64x64) and m = sum_v t_v via MFMA over 32-node chunks.
// Fragment layout (triangulated vs known-good main GEMM): lane&15 = own index,
// (lane>>4)*8+j = k. Both A and B frags for dim-tile f are the SAME data:
// T[k][16f + (lane&15)] -> load once, use as both operands.
__launch_bounds__(256, 2)
__global__ void gram_kernel(const _Float16* __restrict__ t16,
                            float* __restrict__ S,    // [64*64]
                            float* __restrict__ m) {  // [64]
    __shared__ _Float16 tile[4][32 * 64];   // per-wave chunk staging (4 KB each)
    __shared__ float S_lds[64 * 64];
    __shared__ float m_lds[64];
    int lane = threadIdx.x & 63;
    int wblk = threadIdx.x >> 6;
    int quad = lane >> 4;
    int col  = lane & 15;
    for (int i = threadIdx.x; i < 64 * 64; i += 256) S_lds[i] = 0.f;
    if (threadIdx.x < 64) m_lds[threadIdx.x] = 0.f;
    __syncthreads();

    floatx4 acc[4][4];
#pragma unroll
    for (int a = 0; a < 4; ++a)
#pragma unroll
        for (int b = 0; b < 4; ++b) acc[a][b] = floatx4{0.f, 0.f, 0.f, 0.f};
    float macc[4] = {0.f, 0.f, 0.f, 0.f};

    int wid = blockIdx.x * 4 + wblk;          // 0..255
    for (int ch = wid; ch < NCHUNKS; ch += GRAM_BLOCKS * 4) {
        const uint4* src = (const uint4*)(t16 + (size_t)ch * 32 * 64);
        uint4* dst = (uint4*)tile[wblk];
#pragma unroll
        for (int j = 0; j < 4; ++j)
            dst[lane + 64 * j] = src[lane + 64 * j];
        // same-wave DS ops complete in order (R7-verified pattern): reads below see writes
        half8 fr[4];
#pragma unroll
        for (int a = 0; a < 4; ++a) {
            const _Float16* base = tile[wblk] + (size_t)(quad * 8) * 64 + a * 16 + col;
#pragma unroll
            for (int j = 0; j < 8; ++j)
                fr[a][j] = base[(size_t)j * 64];
        }
#pragma unroll
        for (int a = 0; a < 4; ++a) {
            float s = 0.f;
#pragma unroll
            for (int j = 0; j < 8; ++j) s += (float)fr[a][j];
            macc[a] += s;
        }
#pragma unroll
        for (int a = 0; a < 4; ++a)
#pragma unroll
            for (int b = 0; b < 4; ++b)
                acc[a][b] = __builtin_amdgcn_mfma_f32_16x16x32_f16(fr[a], fr[b], acc[a][b], 0, 0, 0);
    }
    // C/D layout: row(A)=16a+quad*4+r, col(B)=16b+col [m89]
#pragma unroll
    for (int a = 0; a < 4; ++a)
#pragma unroll
        for (int b = 0; b < 4; ++b)
#pragma unroll
            for (int r = 0; r < 4; ++r)
                atomicAdd(&S_lds[(a * 16 + quad * 4 + r) * 64 + b * 16 + col], acc[a][b][r]);
#pragma unroll
    for (int a = 0; a < 4; ++a) {
        macc[a] += __shfl_xor(macc[a], 16);
        macc[a] += __shfl_xor(macc[a], 32);
        if (quad == 0) atomicAdd(&m_lds[a * 16 + col], macc[a]);
    }
    __syncthreads();
    for (int i = threadIdx.x; i < 64 * 64; i += 256)
        atomicAdd(&S[i], S_lds[i]);
    if (threadIdx.x < 64) atomicAdd(&m[threadIdx.x], m_lds[threadIdx.x]);
}

// Analytic BN stats: colsum_j = (m@W)_j + N b_j ; colsq_j = (W^T S W)_jj + 2 b_j (m@W)_j + N b_j^2.
// Uses fp16-rounded W (matches wfrag/MFMA arithmetic). Output ss = {scale[64], shift[64]}.
__global__ void stats_kernel(const float* __restrict__ S,
                             const float* __restrict__ m,
                             const float* __restrict__ W,     // [64,64] layer slice (fp32)
                             const float* __restrict__ bias,
                             const float* __restrict__ gamma,
                             const float* __restrict__ beta,
                             float* __restrict__ ss) {
    __shared__ float sS[64 * 64];
    __shared__ float sW[64 * 64];
    __shared__ float su[64 * 64];
    int t = threadIdx.x;   // 256
    for (int i = t; i < 4096; i += 256) {
        sS[i] = S[i];
        sW[i] = (float)(_Float16)W[i];
    }
    __syncthreads();
    for (int p = t; p < 4096; p += 256) {
        int d = p >> 6, j = p & 63;
        float s = 0.f;
#pragma unroll 8
        for (int e = 0; e < 64; ++e) s += sS[d * 64 + e] * sW[e * 64 + j];
        su[p] = s;
    }
    __syncthreads();
    if (t < 64) {
        int j = t;
        float mw = 0.f, q2 = 0.f;
        for (int d = 0; d < 64; ++d) {
            mw += m[d] * sW[d * 64 + j];
            q2 += sW[d * 64 + j] * su[d * 64 + j];
        }
        float b = bias[j];
        const float invN = 1.0f / (float)N_NODES;
        float mu  = mw * invN + b;
        float Eq  = (q2 + 2.f * b * mw) * invN + b * b;
        float var = Eq - mu * mu;
        float scv = rsqrtf(var + BN_EPS) * gamma[j];
        ss[j]      = scv;
        ss[64 + j] = beta[j] - mu * scv;
    }
}

// One-pass GEMM + affine-BN + relu + residual (layers 0,1). No grid sync.
__launch_bounds__(256, 2)
__global__ void gemm_bn2(const _Float16* __restrict__ t16,
                         const _Float16* __restrict__ wfrag,
                         const float* __restrict__ bias,
                         const float* __restrict__ ss,   // scale[64], shift[64]
                         float* __restrict__ h,
                         __half* __restrict__ hh) {
    __shared__ float sscale[EMBED];
    __shared__ float sshift[EMBED];
    __shared__ float4 tl[4][16][17];

    int lane = threadIdx.x & 63;
    int wblk = threadIdx.x >> 6;
    int quad = lane >> 4;
    int col  = lane & 15;
    int wid  = blockIdx.x * 4 + wblk;

    if (threadIdx.x < EMBED) {
        sscale[threadIdx.x] = ss[threadIdx.x];
        sshift[threadIdx.x] = ss[64 + threadIdx.x];
    }
    __syncthreads();

    half8 bf[4][2];
#pragma unroll
    for (int nt = 0; nt < 4; ++nt)
#pragma unroll
        for (int kh = 0; kh < 2; ++kh)
            bf[nt][kh] = *(const half8*)(wfrag + ((size_t)(nt * 2 + kh) * 64 + lane) * 8);

    float bj[4], scr[4], shr[4];
#pragma unroll
    for (int nt = 0; nt < 4; ++nt) {
        bj[nt]  = bias[nt * 16 + col];
        scr[nt] = sscale[nt * 16 + col];
        shr[nt] = sshift[nt * 16 + col];
    }

    float4* h4g = (float4*)h;
    uint2*  hh2 = (uint2*)hh;

#pragma unroll
    for (int k = 0; k < TPW; ++k) {
        int tile = wid + k * GB_WAVES;
        if (tile >= NTILES) continue;
        int base = tile * 16;
        size_t tb = (size_t)tile * 256;
        const _Float16* arow = t16 + (size_t)(base + col) * 64 + quad * 8;
        half8 a0 = *(const half8*)(arow);
        half8 a1 = *(const half8*)(arow + 32);
        floatx4 c[4];
#pragma unroll
        for (int nt = 0; nt < 4; ++nt) {
            floatx4 cc = {bj[nt], bj[nt], bj[nt], bj[nt]};
            cc = __builtin_amdgcn_mfma_f32_16x16x32_f16(a0, bf[nt][0], cc, 0, 0, 0);
            cc = __builtin_amdgcn_mfma_f32_16x16x32_f16(a1, bf[nt][1], cc, 0, 0, 0);
            c[nt] = cc;
        }
        // vectorized h-tile load -> LDS (same-wave DS ordering, R7-verified)
#pragma unroll
        for (int j = 0; j < 4; ++j)
            tl[wblk][lane >> 2][(lane & 3) * 4 + j] = h4g[tb + lane * 4 + j];
        // affine + relu + residual in LDS
#pragma unroll
        for (int nt = 0; nt < 4; ++nt) {
            int f4 = nt * 4 + (col >> 2), cm = col & 3;
#pragma unroll
            for (int r = 0; r < 4; ++r) {
                int node = quad * 4 + r;
                float* slot = (float*)&tl[wblk][node][f4] + cm;
                float y = fmaxf(c[nt][r] * scr[nt] + shr[nt], 0.0f);
                *slot = y + *slot;
            }
        }
        // vectorized store h + fp16 mirror
#pragma unroll
        for (int j = 0; j < 4; ++j) {
            float4 o = tl[wblk][lane >> 2][(lane & 3) * 4 + j];
            h4g[tb + lane * 4 + j] = o;
            __half2 m0 = __floats2half2_rn(o.x, o.y);
            __half2 m1 = __floats2half2_rn(o.z, o.w);
            uint2 pk;
            pk.x = *(unsigned*)&m0;
            pk.y = *(unsigned*)&m1;
            hh2[tb + lane * 4 + j] = pk;
        }
    }
}

// Layer-2 one-pass: GEMM + affine-BN (no relu) + residual + graph-pool atomics. No sync.
__launch_bounds__(256, 2)
__global__ void gemm_pool2(const _Float16* __restrict__ t16,
                           const _Float16* __restrict__ wfrag,
                           const float* __restrict__ bias,
                           const float* __restrict__ ss,
                           const float* __restrict__ h,
                           const int* __restrict__ gid,
                           float* __restrict__ gsum) {
    __shared__ float sscale[EMBED];
    __shared__ float sshift[EMBED];
    __shared__ float4 tl[4][16][17];

    int lane = threadIdx.x & 63;
    int wblk = threadIdx.x >> 6;
    int quad = lane >> 4;
    int col  = lane & 15;
    int wid  = blockIdx.x * 4 + wblk;

    if (threadIdx.x < EMBED) {
        sscale[threadIdx.x] = ss[threadIdx.x];
        sshift[threadIdx.x] = ss[64 + threadIdx.x];
    }
    __syncthreads();

    half8 bf[4][2];
#pragma unroll
    for (int nt = 0; nt < 4; ++nt)
#pragma unroll
        for (int kh = 0; kh < 2; ++kh)
            bf[nt][kh] = *(const half8*)(wfrag + ((size_t)(nt * 2 + kh) * 64 + lane) * 8);

    float bj[4], scr[4], shr[4];
#pragma unroll
    for (int nt = 0; nt < 4; ++nt) {
        bj[nt]  = bias[nt * 16 + col];
        scr[nt] = sscale[nt * 16 + col];
        shr[nt] = sshift[nt * 16 + col];
    }

    const float4* h4g = (const float4*)h;

#pragma unroll
    for (int k = 0; k < TPW; ++k) {
        int tile = wid + k * GB_WAVES;
        if (tile >= NTILES) continue;
        int base = tile * 16;
        size_t tb = (size_t)tile * 256;
        const _Float16* arow = t16 + (size_t)(base + col) * 64 + quad * 8;
        half8 a0 = *(const half8*)(arow);
        half8 a1 = *(const half8*)(arow + 32);
        floatx4 c[4];
#pragma unroll
        for (int nt = 0; nt < 4; ++nt) {
            floatx4 cc = {bj[nt], bj[nt], bj[nt], bj[nt]};
            cc = __builtin_amdgcn_mfma_f32_16x16x32_f16(a0, bf[nt][0], cc, 0, 0, 0);
            cc = __builtin_amdgcn_mfma_f32_16x16x32_f16(a1, bf[nt][1], cc, 0, 0, 0);
            c[nt] = cc;
        }
#pragma unroll
        for (int j = 0; j < 4; ++j)
            tl[wblk][lane >> 2][(lane & 3) * 4 + j] = h4g[tb + lane * 4 + j];

        int g0  = gid[base];
        int g15 = gid[base + 15];
        float val[4][4];   // [nt][r]
#pragma unroll
        for (int nt = 0; nt < 4; ++nt) {
            int f4 = nt * 4 + (col >> 2), cm = col & 3;
#pragma unroll
            for (int r = 0; r < 4; ++r) {
                int node = quad * 4 + r;
                float hval = ((const float*)&tl[wblk][node][f4])[cm];
                val[nt][r] = c[nt][r] * scr[nt] + shr[nt] + hval;   // no relu, + residual
            }
        }
        if (g0 == g15) {   // tile-uniform graph: one wave-reduced atomic per (nt,col)
#pragma unroll
            for (int nt = 0; nt < 4; ++nt) {
                float s = val[nt][0] + val[nt][1] + val[nt][2] + val[nt][3];
                s += __shfl_xor(s, 16);
                s += __shfl_xor(s, 32);
                if (quad == 0)
                    atomicAdd(&gsum[(size_t)g0 * EMBED + nt * 16 + col], s);
            }
        } else {
#pragma unroll
            for (int r = 0; r < 4; ++r) {
                int node = base + quad * 4 + r;
                int g = gid[node];
#pragma unroll
                for (int nt = 0; nt < 4; ++nt)
                    atomicAdd(&gsum[(size_t)g * EMBED + nt * 16 + col], val[nt][r]);
            }
        }
    }
}

// pred: block per graph; gm = gsum/cnt; out = gm @ predW + predb
__global__ void pred_kernel(const int* __restrict__ gstart,
                            const float* __restrict__ gsum,
                            const float* __restrict__ predW,  // [64,128]
                            const float* __restrict__ predb,  // [128]
                            float* __restrict__ out) {        // [G,128]
    __shared__ float gm[EMBED];
    int g = blockIdx.x;
    if (threadIdx.x < EMBED) {
        int nb = gstart[g], ne = gstart[g + 1];
        gm[threadIdx.x] = gsum[(size_t)g * EMBED + threadIdx.x]
                        / fmaxf((float)(ne - nb), 1.0f);
    }
    __syncthreads();
    float acc = predb[threadIdx.x];
#pragma unroll
    for (int d = 0; d < EMBED; ++d)
        acc += gm[d] * predW[d * OUT_DIM + threadIdx.x];
    out[g * OUT_DIM + threadIdx.x] = acc;
}

// ---------------- launch ----------------

extern "C" void kernel_launch(void* const* d_in, const int* in_sizes, int n_in,
                              void* d_out, int out_size, void* d_ws, size_t ws_size,
                              hipStream_t stream) {
    const int*   nfeat      = (const int*)d_in[0];
    const int*   efeat      = (const int*)d_in[1];
    const int*   src        = (const int*)d_in[2];
    const int*   dst        = (const int*)d_in[3];
    const int*   gid        = (const int*)d_in[4];
    const float* atom_embed = (const float*)d_in[5];
    const float* bond_embed = (const float*)d_in[6];  // [3,5,64]
    const float* conv_W     = (const float*)d_in[7];  // [3,64,64]
    const float* conv_b     = (const float*)d_in[8];  // [3,64]
    const float* bn_gamma   = (const float*)d_in[9];  // [3,64]
    const float* bn_beta    = (const float*)d_in[10]; // [3,64]
    const float* pred_W     = (const float*)d_in[11]; // [64,128]
    const float* pred_b     = (const float*)d_in[12]; // [128]
    float* out = (float*)d_out;

    char* wsb = (char*)d_ws;
    float*     h        = (float*)wsb;                  wsb += (size_t)N_NODES * EMBED * 4;
    _Float16*  t16      = (_Float16*)wsb;               wsb += (size_t)N_NODES * EMBED * 2;
    __half*    hh       = (__half*)wsb;                 wsb += (size_t)N_NODES * EMBED * 2;
    _Float16*  wfrag    = (_Float16*)wsb;               wsb += (size_t)3 * 4096 * 2;
    unsigned*  binned   = (unsigned*)wsb;               wsb += (size_t)N_EDGES * 4;
    unsigned*  ebuf     = (unsigned*)wsb;               wsb += (size_t)N_EDGES * 4;
    int*       blockhist= (int*)wsb;                    wsb += (size_t)NBINS * NSCB * 4;
    int*       gofs     = (int*)wsb;                    wsb += (size_t)NBINS * NSCB * 4;
    int*       total    = (int*)wsb;                    wsb += (size_t)NBINS * 4;
    int*       binoff   = (int*)wsb;                    wsb += (size_t)(NBINS + 1) * 4;
    int*       rowptr   = (int*)wsb;                    wsb += (size_t)(N_NODES + 1) * 4;
    int*       gstart   = (int*)wsb;                    wsb += (size_t)(N_GRAPHS + 1) * 4;
    float*     Sbuf     = (float*)wsb;                  wsb += (size_t)3 * 4096 * 4;  // + mbuf adjacent
    float*     mbuf     = (float*)wsb;                  wsb += (size_t)3 * 64 * 4;
    float*     ssbuf    = (float*)wsb;                  wsb += (size_t)3 * 128 * 4;
    float*     gsum     = (float*)wsb;                  wsb += (size_t)N_GRAPHS * EMBED * 4;

    embed_kernel<<<(N_NODES * 16 + 255) / 256, 256, 0, stream>>>(
        nfeat, atom_embed, (float4*)h, hh, gid, gstart, gsum);
    hist2_kernel<<<NSCB, 256, 0, stream>>>(dst, blockhist);
    binreduce_kernel<<<NBINS, NSCB, 0, stream>>>(blockhist, gofs, total);
    binscan_kernel<<<1, 1024, 0, stream>>>(total, binoff, Sbuf, conv_W, wfrag);
    binscatter_kernel<<<NSCB, 256, 0, stream>>>(src, dst, efeat, binoff, gofs, binned);
    bincsr_kernel<<<NBINS, 256, 0, stream>>>(binned, binoff, rowptr, ebuf);

    for (int i = 0; i < 3; ++i) {
        gather_kernel<<<1536, 256, 0, stream>>>(
            rowptr, ebuf, bond_embed + i * 5 * EMBED, hh, h, (__half*)t16);
        float* Si = Sbuf + (size_t)i * 4096;
        float* mi = mbuf + (size_t)i * 64;
        float* ssi = ssbuf + (size_t)i * 128;
        gram_kernel<<<GRAM_BLOCKS, 256, 0, stream>>>((const _Float16*)t16, Si, mi);
        stats_kernel<<<1, 256, 0, stream>>>(
            Si, mi, conv_W + (size_t)i * 4096, conv_b + (size_t)i * EMBED,
            bn_gamma + (size_t)i * EMBED, bn_beta + (size_t)i * EMBED, ssi);
        const _Float16* wf = wfrag + (size_t)i * 4096;
        const float* bi = conv_b + (size_t)i * EMBED;
        if (i != 2) {
            gemm_bn2<<<GB_BLOCKS, 256, 0, stream>>>(
                (const _Float16*)t16, wf, bi, ssi, h, hh);
        } else {
            gemm_pool2<<<GB_BLOCKS, 256, 0, stream>>>(
                (const _Float16*)t16, wf, bi, ssi, h, gid, gsum);
        }
    }
    pred_kernel<<<N_GRAPHS, OUT_DIM, 0, stream>>>(gstart, gsum, pred_W, pred_b, out);
}

// Round 9
// 430.947 us; speedup vs baseline: 1.0509x; 1.0509x over previous
//
#include <hip/hip_runtime.h>
#include <hip/hip_fp16.h>

#define N_NODES 100000
#define N_EDGES 1000000
#define N_GRAPHS 1000
#define EMBED 64
#define OUT_DIM 128
#define BN_EPS 1e-5f
#define NBINS 782                          // dst>>7 -> 128 nodes per bin
#define NSCB 512                           // scatter blocks (fixed edge ranges)
#define EPB ((N_EDGES + NSCB - 1) / NSCB)  // 1954 edges per block
#define NTILES (N_NODES / 16)              // 6250 exact

#define GB_BLOCKS 512
#define GB_WAVES (GB_BLOCKS * 4)           // 2048 waves
#define TPW 4                              // ceil(6250/2048) tiles per wave
#define GRAM_BLOCKS 128
#define NCHUNKS (N_NODES / 32)             // 3125 exact

typedef _Float16 half8 __attribute__((ext_vector_type(8)));
typedef float floatx4 __attribute__((ext_vector_type(4)));

// Barrier-free BN (R8 structure, R9 tuning): stats computed analytically from
// m = sum_v t_v and S = sum_v t_v t_v^T, since h_pre = t@W+b gives
// colsum = m@W + N b and colsq_j = (W^T S W)_jj + 2 b_j (m@W)_j + N b_j^2.
// Per layer: gather -> gram -> stats(tiny) -> one-pass gemm+bn. Zero grid barriers.
// R8 run was infra-degraded (425s push, fresh container); decision rule: if a healthy
// run lands >=400us, revert to R7 fused-barrier structure.

// ---------------- one-time structure kernels ----------------

__global__ void embed_kernel(const int* __restrict__ nfeat,
                             const float* __restrict__ atom_embed,
                             float4* __restrict__ h4,
                             __half* __restrict__ hh,
                             const int* __restrict__ gid,
                             int* __restrict__ gstart,
                             float* __restrict__ gsum) {
    int idx = blockIdx.x * blockDim.x + threadIdx.x;   // one float4 each
    if (idx <= N_NODES) {   // folded gbound
        int cur  = (idx < N_NODES) ? gid[idx] : N_GRAPHS;
        int prev = (idx == 0) ? -1 : gid[idx - 1];
        for (int g = prev + 1; g <= cur; ++g) gstart[g] = idx;
    }
    if (idx < N_GRAPHS * EMBED) gsum[idx] = 0.0f;
    if (idx >= N_NODES * 16) return;
    int v = idx >> 4, q = idx & 15;
    const float4* ae = (const float4*)atom_embed;
    float4 val = ae[nfeat[v] * 16 + q];
    h4[idx] = val;
    __half2 m0 = __floats2half2_rn(val.x, val.y);
    __half2 m1 = __floats2half2_rn(val.z, val.w);
    uint2 packed;
    packed.x = *(unsigned*)&m0;
    packed.y = *(unsigned*)&m1;
    ((uint2*)hh)[idx] = packed;
}

__global__ void hist2_kernel(const int* __restrict__ dst, int* __restrict__ blockhist) {
    __shared__ int hist[NBINS];
    for (int i = threadIdx.x; i < NBINS; i += 256) hist[i] = 0;
    __syncthreads();
    int b = blockIdx.x;
    int e0 = b * EPB, e1 = min(e0 + EPB, N_EDGES);
    for (int e = e0 + threadIdx.x; e < e1; e += 256)
        atomicAdd(&hist[dst[e] >> 7], 1);
    __syncthreads();
    for (int i = threadIdx.x; i < NBINS; i += 256)
        blockhist[i * NSCB + b] = hist[i];
}

__global__ void binreduce_kernel(const int* __restrict__ blockhist,
                                 int* __restrict__ gofs, int* __restrict__ total) {
    __shared__ int sm[NSCB];
    int bin = blockIdx.x;
    int i = threadIdx.x;   // 0..511
    int orig = blockhist[bin * NSCB + i];
    sm[i] = orig;
    __syncthreads();
    for (int off = 1; off < NSCB; off <<= 1) {
        int val = sm[i];
        if (i >= off) val += sm[i - off];
        __syncthreads();
        sm[i] = val;
        __syncthreads();
    }
    gofs[bin * NSCB + i] = sm[i] - orig;   // exclusive within bin
    if (i == NSCB - 1) total[bin] = sm[i];
}

// scan bin totals -> binoff; zero S/m accumulators; pack W frags
__global__ void binscan_kernel(const int* __restrict__ total,
                               int* __restrict__ binoff, float* __restrict__ zbuf,
                               const float* __restrict__ conv_W,
                               _Float16* __restrict__ wfrag) {
    __shared__ int sm[1024];
    int i = threadIdx.x;
    for (int s = i; s < 3 * 4096 + 3 * 64; s += 1024) zbuf[s] = 0.0f;  // Sbuf + mbuf
    // folded wpack: 3 layers x 512 slots
    for (int s = i; s < 3 * 512; s += 1024) {
        int L = s >> 9, slot = s & 511;
        int lane = slot & 63;
        int f = slot >> 6;          // nt*2+kh
        int nt = f >> 1, kh = f & 1;
        int n  = nt * 16 + (lane & 15);
        int k0 = kh * 32 + (lane >> 4) * 8;
        const float* W = conv_W + L * 4096;
        _Float16* out = wfrag + L * 4096;
#pragma unroll
        for (int j = 0; j < 8; ++j)
            out[slot * 8 + j] = (_Float16)W[(k0 + j) * 64 + n];
    }
    int orig = (i < NBINS) ? total[i] : 0;
    sm[i] = orig;
    __syncthreads();
    for (int off = 1; off < 1024; off <<= 1) {
        int val = sm[i];
        if (i >= off) val += sm[i - off];
        __syncthreads();
        sm[i] = val;
        __syncthreads();
    }
    if (i < NBINS) binoff[i] = sm[i] - orig;
    if (i == 0) binoff[NBINS] = N_EDGES;
}

__global__ void binscatter_kernel(const int* __restrict__ src, const int* __restrict__ dst,
                                  const int* __restrict__ efeat,
                                  const int* __restrict__ binoff, const int* __restrict__ gofs,
                                  unsigned* __restrict__ binned) {
    __shared__ int cur[NBINS];
    int b = blockIdx.x;
    for (int i = threadIdx.x; i < NBINS; i += 256)
        cur[i] = binoff[i] + gofs[i * NSCB + b];
    __syncthreads();
    int e0 = b * EPB, e1 = min(e0 + EPB, N_EDGES);
    for (int e = e0 + threadIdx.x; e < e1; e += 256) {
        int t = dst[e];
        int bin = t >> 7;
        int pos = atomicAdd(&cur[bin], 1);   // LDS atomic
        binned[pos] = (unsigned)src[e] | ((unsigned)efeat[e] << 17)
                    | ((unsigned)(t & 127) << 20);
    }
}

__global__ void bincsr_kernel(const unsigned* __restrict__ binned,
                              const int* __restrict__ binoff,
                              int* __restrict__ rowptr,
                              unsigned* __restrict__ ebuf) {
    __shared__ int cnt[128];
    __shared__ int sc[128];
    int b = blockIdx.x;
    int tid = threadIdx.x;
    int base = binoff[b], end = binoff[b + 1];

    if (tid < 128) cnt[tid] = 0;
    __syncthreads();

    for (int i = base + tid; i < end; i += 256)
        atomicAdd(&cnt[binned[i] >> 20], 1);
    __syncthreads();

    if (tid < 128) sc[tid] = cnt[tid];
    __syncthreads();
    for (int off = 1; off < 128; off <<= 1) {
        int val = 0;
        if (tid < 128) {
            val = sc[tid];
            if (tid >= off) val += sc[tid - off];
        }
        __syncthreads();
        if (tid < 128) sc[tid] = val;
        __syncthreads();
    }
    if (tid < 128) {
        int excl = sc[tid] - cnt[tid];
        int v = b * 128 + tid;
        if (v < N_NODES) rowptr[v] = base + excl;
        cnt[tid] = excl;   // becomes running cursor
    }
    if (b == 0 && tid == 255) rowptr[N_NODES] = N_EDGES;
    __syncthreads();

    for (int i = base + tid; i < end; i += 256) {
        unsigned rec = binned[i];
        int dl = rec >> 20;
        int pos = base + atomicAdd(&cnt[dl], 1);
        ebuf[pos] = (rec & 0x1FFFFu) | (((rec >> 17) & 0x7u) << 20);
    }
}

// ---------------- per-layer kernels ----------------

// Gather: quarter-wave per node. At the random-line service-rate wall (R6/R10/R18).
__launch_bounds__(256, 6)
__global__ void gather_kernel(const int* __restrict__ rowptr,
                              const unsigned* __restrict__ ebuf,
                              const float* __restrict__ bond,    // [5,64]
                              const __half* __restrict__ hh,     // fp16 mirror
                              const float* __restrict__ hmast,   // fp32 master
                              __half* __restrict__ t16) {
    __shared__ float bond_s[5 * EMBED];
    for (int i = threadIdx.x; i < 5 * EMBED; i += 256) bond_s[i] = bond[i];
    __syncthreads();

    int sl = threadIdx.x & 15;    // uint2 slot: dims 4sl..4sl+3
    int d0 = sl * 4;
    int gq = (blockIdx.x * 256 + threadIdx.x) >> 4;   // global quarter id
    int nq = (gridDim.x * 256) >> 4;
    const uint2* hhq = (const uint2*)hh;    // 16 uint2 per node row

    for (int v = gq; v < N_NODES; v += nq) {
        int rb = rowptr[v], re = rowptr[v + 1];
        float4 a0 = {0,0,0,0}, a1 = {0,0,0,0}, a2 = {0,0,0,0}, a3 = {0,0,0,0};
        int e = rb;
        for (; e + 4 <= re; e += 4) {
            unsigned p0 = ebuf[e + 0];
            unsigned p1 = ebuf[e + 1];
            unsigned p2 = ebuf[e + 2];
            unsigned p3 = ebuf[e + 3];
            uint2 g0 = hhq[(size_t)(p0 & 0xFFFFFu) * 16 + sl];
            uint2 g1 = hhq[(size_t)(p1 & 0xFFFFFu) * 16 + sl];
            uint2 g2 = hhq[(size_t)(p2 & 0xFFFFFu) * 16 + sl];
            uint2 g3 = hhq[(size_t)(p3 & 0xFFFFFu) * 16 + sl];
            const float* c0 = &bond_s[(p0 >> 20) * EMBED + d0];
            const float* c1 = &bond_s[(p1 >> 20) * EMBED + d0];
            const float* c2 = &bond_s[(p2 >> 20) * EMBED + d0];
            const float* c3 = &bond_s[(p3 >> 20) * EMBED + d0];
            float2 f0a = __half22float2(*(const __half2*)&g0.x);
            float2 f0b = __half22float2(*(const __half2*)&g0.y);
            float2 f1a = __half22float2(*(const __half2*)&g1.x);
            float2 f1b = __half22float2(*(const __half2*)&g1.y);
            float2 f2a = __half22float2(*(const __half2*)&g2.x);
            float2 f2b = __half22float2(*(const __half2*)&g2.y);
            float2 f3a = __half22float2(*(const __half2*)&g3.x);
            float2 f3b = __half22float2(*(const __half2*)&g3.y);
            a0.x += fmaxf(f0a.x + c0[0], 0.f); a0.y += fmaxf(f0a.y + c0[1], 0.f);
            a0.z += fmaxf(f0b.x + c0[2], 0.f); a0.w += fmaxf(f0b.y + c0[3], 0.f);
            a1.x += fmaxf(f1a.x + c1[0], 0.f); a1.y += fmaxf(f1a.y + c1[1], 0.f);
            a1.z += fmaxf(f1b.x + c1[2], 0.f); a1.w += fmaxf(f1b.y + c1[3], 0.f);
            a2.x += fmaxf(f2a.x + c2[0], 0.f); a2.y += fmaxf(f2a.y + c2[1], 0.f);
            a2.z += fmaxf(f2b.x + c2[2], 0.f); a2.w += fmaxf(f2b.y + c2[3], 0.f);
            a3.x += fmaxf(f3a.x + c3[0], 0.f); a3.y += fmaxf(f3a.y + c3[1], 0.f);
            a3.z += fmaxf(f3b.x + c3[2], 0.f); a3.w += fmaxf(f3b.y + c3[3], 0.f);
        }
        for (; e < re; ++e) {
            unsigned p = ebuf[e];
            uint2 g = hhq[(size_t)(p & 0xFFFFFu) * 16 + sl];
            const float* c = &bond_s[(p >> 20) * EMBED + d0];
            float2 fa = __half22float2(*(const __half2*)&g.x);
            float2 fb = __half22float2(*(const __half2*)&g.y);
            a0.x += fmaxf(fa.x + c[0], 0.f); a0.y += fmaxf(fa.y + c[1], 0.f);
            a0.z += fmaxf(fb.x + c[2], 0.f); a0.w += fmaxf(fb.y + c[3], 0.f);
        }
        float inv = 1.0f / fmaxf((float)(re - rb), 1.0f);
        float4 hr = ((const float4*)hmast)[(size_t)v * 16 + sl];
        float tx = (a0.x + a1.x + a2.x + a3.x) * inv + hr.x;
        float ty = (a0.y + a1.y + a2.y + a3.y) * inv + hr.y;
        float tz = (a0.z + a1.z + a2.z + a3.z) * inv + hr.z;
        float tw = (a0.w + a1.w + a2.w + a3.w) * inv + hr.w;
        __half2 m0 = __floats2half2_rn(tx, ty);
        __half2 m1 = __floats2half2_rn(tz, tw);
        uint2 packed;
        packed.x = *(unsigned*)&m0;
        packed.y = *(unsigned*)&m1;
        ((uint2*)t16)[(size_t)v * 16 + sl] = packed;
    }
}

// Gram: S = sum_v t_v t_v^T (64x64) and m = sum_v t_v via MFMA over 32-node chunks.
// A and B frags for dim-tile f are the same data T[k][16f+(lane&15)], k=(lane>>4)*8+j.
// R9: 128 blocks (512 waves, ~6 chunks each) + next-chunk global prefetch into regs
// hides the ~900cy HBM latency that was the per-chunk critical path at 64 blocks.
__launch_bounds__(256, 2)
__global__ void gram_kernel(const _Float16* __restrict__ t16,
                            float* __restrict__ S,    // [64*64]
                            float* __restrict__ m) {  // [64]
    __shared__ _Float16 tile[4][32 * 64];   // per-wave chunk staging (4 KB each)
    __shared__ float S_lds[64 * 64];
    __shared__ float m_lds[64];
    int lane = threadIdx.x & 63;
    int wblk = threadIdx.x >> 6;
    int quad = lane >> 4;
    int col  = lane & 15;
    for (int i = threadIdx.x; i < 64 * 64; i += 256) S_lds[i] = 0.f;
    if (threadIdx.x < 64) m_lds[threadIdx.x] = 0.f;
    __syncthreads();

    floatx4 acc[4][4];
#pragma unroll
    for (int a = 0; a < 4; ++a)
#pragma unroll
        for (int b = 0; b < 4; ++b) acc[a][b] = floatx4{0.f, 0.f, 0.f, 0.f};
    float macc[4] = {0.f, 0.f, 0.f, 0.f};

    const int stride = GRAM_BLOCKS * 4;
    int wid = blockIdx.x * 4 + wblk;          // 0..511
    uint4 pf[4];
    bool have = (wid < NCHUNKS);
    if (have) {
        const uint4* src = (const uint4*)(t16 + (size_t)wid * 32 * 64);
#pragma unroll
        for (int j = 0; j < 4; ++j) pf[j] = src[lane + 64 * j];
    }
    for (int ch = wid; ch < NCHUNKS; ch += stride) {
        uint4* dst = (uint4*)tile[wblk];
#pragma unroll
        for (int j = 0; j < 4; ++j) dst[lane + 64 * j] = pf[j];
        // prefetch next chunk while we compute this one
        int nxt = ch + stride;
        if (nxt < NCHUNKS) {
            const uint4* src = (const uint4*)(t16 + (size_t)nxt * 32 * 64);
#pragma unroll
            for (int j = 0; j < 4; ++j) pf[j] = src[lane + 64 * j];
        }
        // same-wave DS ordering: reads below see this wave's writes
        half8 fr[4];
#pragma unroll
        for (int a = 0; a < 4; ++a) {
            const _Float16* base = tile[wblk] + (size_t)(quad * 8) * 64 + a * 16 + col;
#pragma unroll
            for (int j = 0; j < 8; ++j)
                fr[a][j] = base[(size_t)j * 64];
        }
#pragma unroll
        for (int a = 0; a < 4; ++a) {
            float s = 0.f;
#pragma unroll
            for (int j = 0; j < 8; ++j) s += (float)fr[a][j];
            macc[a] += s;
        }
#pragma unroll
        for (int a = 0; a < 4; ++a)
#pragma unroll
            for (int b = 0; b < 4; ++b)
                acc[a][b] = __builtin_amdgcn_mfma_f32_16x16x32_f16(fr[a], fr[b], acc[a][b], 0, 0, 0);
    }
    // C/D layout: row(A)=16a+quad*4+r, col(B)=16b+col [m89]
#pragma unroll
    for (int a = 0; a < 4; ++a)
#pragma unroll
        for (int b = 0; b < 4; ++b)
#pragma unroll
            for (int r = 0; r < 4; ++r)
                atomicAdd(&S_lds[(a * 16 + quad * 4 + r) * 64 + b * 16 + col], acc[a][b][r]);
#pragma unroll
    for (int a = 0; a < 4; ++a) {
        macc[a] += __shfl_xor(macc[a], 16);
        macc[a] += __shfl_xor(macc[a], 32);
        if (quad == 0) atomicAdd(&m_lds[a * 16 + col], macc[a]);
    }
    __syncthreads();
    for (int i = threadIdx.x; i < 64 * 64; i += 256)
        atomicAdd(&S[i], S_lds[i]);
    if (threadIdx.x < 64) atomicAdd(&m[threadIdx.x], m_lds[threadIdx.x]);
}

// Analytic BN stats: colsum_j = (m@W)_j + N b_j ; colsq_j = (W^T S W)_jj + 2 b_j (m@W)_j + N b_j^2.
// Uses fp16-rounded W (matches wfrag/MFMA arithmetic). Output ss = {scale[64], shift[64]}.
__global__ void stats_kernel(const float* __restrict__ S,
                             const float* __restrict__ m,
                             const float* __restrict__ W,     // [64,64] layer slice (fp32)
                             const float* __restrict__ bias,
                             const float* __restrict__ gamma,
                             const float* __restrict__ beta,
                             float* __restrict__ ss) {
    __shared__ float sS[64 * 64];
    __shared__ float sW[64 * 64];
    __shared__ float su[64 * 64];
    int t = threadIdx.x;   // 256
    for (int i = t; i < 4096; i += 256) {
        sS[i] = S[i];
        sW[i] = (float)(_Float16)W[i];
    }
    __syncthreads();
    for (int p = t; p < 4096; p += 256) {
        int d = p >> 6, j = p & 63;
        float s = 0.f;
#pragma unroll 8
        for (int e = 0; e < 64; ++e) s += sS[d * 64 + e] * sW[e * 64 + j];
        su[p] = s;
    }
    __syncthreads();
    if (t < 64) {
        int j = t;
        float mw = 0.f, q2 = 0.f;
        for (int d = 0; d < 64; ++d) {
            mw += m[d] * sW[d * 64 + j];
            q2 += sW[d * 64 + j] * su[d * 64 + j];
        }
        float b = bias[j];
        const float invN = 1.0f / (float)N_NODES;
        float mu  = mw * invN + b;
        float Eq  = (q2 + 2.f * b * mw) * invN + b * b;
        float var = Eq - mu * mu;
        float scv = rsqrtf(var + BN_EPS) * gamma[j];
        ss[j]      = scv;
        ss[64 + j] = beta[j] - mu * scv;
    }
}

// One-pass GEMM + affine-BN + relu + residual (layers 0,1). No grid sync.
__launch_bounds__(256, 2)
__global__ void gemm_bn2(const _Float16* __restrict__ t16,
                         const _Float16* __restrict__ wfrag,
                         const float* __restrict__ bias,
                         const float* __restrict__ ss,   // scale[64], shift[64]
                         float* __restrict__ h,
                         __half* __restrict__ hh) {
    __shared__ float sscale[EMBED];
    __shared__ float sshift[EMBED];
    __shared__ float4 tl[4][16][17];

    int lane = threadIdx.x & 63;
    int wblk = threadIdx.x >> 6;
    int quad = lane >> 4;
    int col  = lane & 15;
    int wid  = blockIdx.x * 4 + wblk;

    if (threadIdx.x < EMBED) {
        sscale[threadIdx.x] = ss[threadIdx.x];
        sshift[threadIdx.x] = ss[64 + threadIdx.x];
    }
    __syncthreads();

    half8 bf[4][2];
#pragma unroll
    for (int nt = 0; nt < 4; ++nt)
#pragma unroll
        for (int kh = 0; kh < 2; ++kh)
            bf[nt][kh] = *(const half8*)(wfrag + ((size_t)(nt * 2 + kh) * 64 + lane) * 8);

    float bj[4], scr[4], shr[4];
#pragma unroll
    for (int nt = 0; nt < 4; ++nt) {
        bj[nt]  = bias[nt * 16 + col];
        scr[nt] = sscale[nt * 16 + col];
        shr[nt] = sshift[nt * 16 + col];
    }

    float4* h4g = (float4*)h;
    uint2*  hh2 = (uint2*)hh;

#pragma unroll
    for (int k = 0; k < TPW; ++k) {
        int tile = wid + k * GB_WAVES;
        if (tile >= NTILES) continue;
        int base = tile * 16;
        size_t tb = (size_t)tile * 256;
        const _Float16* arow = t16 + (size_t)(base + col) * 64 + quad * 8;
        half8 a0 = *(const half8*)(arow);
        half8 a1 = *(const half8*)(arow + 32);
        floatx4 c[4];
#pragma unroll
        for (int nt = 0; nt < 4; ++nt) {
            floatx4 cc = {bj[nt], bj[nt], bj[nt], bj[nt]};
            cc = __builtin_amdgcn_mfma_f32_16x16x32_f16(a0, bf[nt][0], cc, 0, 0, 0);
            cc = __builtin_amdgcn_mfma_f32_16x16x32_f16(a1, bf[nt][1], cc, 0, 0, 0);
            c[nt] = cc;
        }
        // vectorized h-tile load -> LDS (same-wave DS ordering)
#pragma unroll
        for (int j = 0; j < 4; ++j)
            tl[wblk][lane >> 2][(lane & 3) * 4 + j] = h4g[tb + lane * 4 + j];
        // affine + relu + residual in LDS
#pragma unroll
        for (int nt = 0; nt < 4; ++nt) {
            int f4 = nt * 4 + (col >> 2), cm = col & 3;
#pragma unroll
            for (int r = 0; r < 4; ++r) {
                int node = quad * 4 + r;
                float* slot = (float*)&tl[wblk][node][f4] + cm;
                float y = fmaxf(c[nt][r] * scr[nt] + shr[nt], 0.0f);
                *slot = y + *slot;
            }
        }
        // vectorized store h + fp16 mirror
#pragma unroll
        for (int j = 0; j < 4; ++j) {
            float4 o = tl[wblk][lane >> 2][(lane & 3) * 4 + j];
            h4g[tb + lane * 4 + j] = o;
            __half2 m0 = __floats2half2_rn(o.x, o.y);
            __half2 m1 = __floats2half2_rn(o.z, o.w);
            uint2 pk;
            pk.x = *(unsigned*)&m0;
            pk.y = *(unsigned*)&m1;
            hh2[tb + lane * 4 + j] = pk;
        }
    }
}

// Layer-2 one-pass: GEMM + affine-BN (no relu) + residual + graph-pool atomics. No sync.
__launch_bounds__(256, 2)
__global__ void gemm_pool2(const _Float16* __restrict__ t16,
                           const _Float16* __restrict__ wfrag,
                           const float* __restrict__ bias,
                           const float* __restrict__ ss,
                           const float* __restrict__ h,
                           const int* __restrict__ gid,
                           float* __restrict__ gsum) {
    __shared__ float sscale[EMBED];
    __shared__ float sshift[EMBED];
    __shared__ float4 tl[4][16][17];

    int lane = threadIdx.x & 63;
    int wblk = threadIdx.x >> 6;
    int quad = lane >> 4;
    int col  = lane & 15;
    int wid  = blockIdx.x * 4 + wblk;

    if (threadIdx.x < EMBED) {
        sscale[threadIdx.x] = ss[threadIdx.x];
        sshift[threadIdx.x] = ss[64 + threadIdx.x];
    }
    __syncthreads();

    half8 bf[4][2];
#pragma unroll
    for (int nt = 0; nt < 4; ++nt)
#pragma unroll
        for (int kh = 0; kh < 2; ++kh)
            bf[nt][kh] = *(const half8*)(wfrag + ((size_t)(nt * 2 + kh) * 64 + lane) * 8);

    float bj[4], scr[4], shr[4];
#pragma unroll
    for (int nt = 0; nt < 4; ++nt) {
        bj[nt]  = bias[nt * 16 + col];
        scr[nt] = sscale[nt * 16 + col];
        shr[nt] = sshift[nt * 16 + col];
    }

    const float4* h4g = (const float4*)h;

#pragma unroll
    for (int k = 0; k < TPW; ++k) {
        int tile = wid + k * GB_WAVES;
        if (tile >= NTILES) continue;
        int base = tile * 16;
        size_t tb = (size_t)tile * 256;
        const _Float16* arow = t16 + (size_t)(base + col) * 64 + quad * 8;
        half8 a0 = *(const half8*)(arow);
        half8 a1 = *(const half8*)(arow + 32);
        floatx4 c[4];
#pragma unroll
        for (int nt = 0; nt < 4; ++nt) {
            floatx4 cc = {bj[nt], bj[nt], bj[nt], bj[nt]};
            cc = __builtin_amdgcn_mfma_f32_16x16x32_f16(a0, bf[nt][0], cc, 0, 0, 0);
            cc = __builtin_amdgcn_mfma_f32_16x16x32_f16(a1, bf[nt][1], cc, 0, 0, 0);
            c[nt] = cc;
        }
#pragma unroll
        for (int j = 0; j < 4; ++j)
            tl[wblk][lane >> 2][(lane & 3) * 4 + j] = h4g[tb + lane * 4 + j];

        int g0  = gid[base];
        int g15 = gid[base + 15];
        float val[4][4];   // [nt][r]
#pragma unroll
        for (int nt = 0; nt < 4; ++nt) {
            int f4 = nt * 4 + (col >> 2), cm = col & 3;
#pragma unroll
            for (int r = 0; r < 4; ++r) {
                int node = quad * 4 + r;
                float hval = ((const float*)&tl[wblk][node][f4])[cm];
                val[nt][r] = c[nt][r] * scr[nt] + shr[nt] + hval;   // no relu, + residual
            }
        }
        if (g0 == g15) {   // tile-uniform graph: one wave-reduced atomic per (nt,col)
#pragma unroll
            for (int nt = 0; nt < 4; ++nt) {
                float s = val[nt][0] + val[nt][1] + val[nt][2] + val[nt][3];
                s += __shfl_xor(s, 16);
                s += __shfl_xor(s, 32);
                if (quad == 0)
                    atomicAdd(&gsum[(size_t)g0 * EMBED + nt * 16 + col], s);
            }
        } else {
#pragma unroll
            for (int r = 0; r < 4; ++r) {
                int node = base + quad * 4 + r;
                int g = gid[node];
#pragma unroll
                for (int nt = 0; nt < 4; ++nt)
                    atomicAdd(&gsum[(size_t)g * EMBED + nt * 16 + col], val[nt][r]);
            }
        }
    }
}

// pred: block per graph; gm = gsum/cnt; out = gm @ predW + predb
__global__ void pred_kernel(const int* __restrict__ gstart,
                            const float* __restrict__ gsum,
                            const float* __restrict__ predW,  // [64,128]
                            const float* __restrict__ predb,  // [128]
                            float* __restrict__ out) {        // [G,128]
    __shared__ float gm[EMBED];
    int g = blockIdx.x;
    if (threadIdx.x < EMBED) {
        int nb = gstart[g], ne = gstart[g + 1];
        gm[threadIdx.x] = gsum[(size_t)g * EMBED + threadIdx.x]
                        / fmaxf((float)(ne - nb), 1.0f);
    }
    __syncthreads();
    float acc = predb[threadIdx.x];
#pragma unroll
    for (int d = 0; d < EMBED; ++d)
        acc += gm[d] * predW[d * OUT_DIM + threadIdx.x];
    out[g * OUT_DIM + threadIdx.x] = acc;
}

// ---------------- launch ----------------

extern "C" void kernel_launch(void* const* d_in, const int* in_sizes, int n_in,
                              void* d_out, int out_size, void* d_ws, size_t ws_size,
                              hipStream_t stream) {
    const int*   nfeat      = (const int*)d_in[0];
    const int*   efeat      = (const int*)d_in[1];
    const int*   src        = (const int*)d_in[2];
    const int*   dst        = (const int*)d_in[3];
    const int*   gid        = (const int*)d_in[4];
    const float* atom_embed = (const float*)d_in[5];
    const float* bond_embed = (const float*)d_in[6];  // [3,5,64]
    const float* conv_W     = (const float*)d_in[7];  // [3,64,64]
    const float* conv_b     = (const float*)d_in[8];  // [3,64]
    const float* bn_gamma   = (const float*)d_in[9];  // [3,64]
    const float* bn_beta    = (const float*)d_in[10]; // [3,64]
    const float* pred_W     = (const float*)d_in[11]; // [64,128]
    const float* pred_b     = (const float*)d_in[12]; // [128]
    float* out = (float*)d_out;

    char* wsb = (char*)d_ws;
    float*     h        = (float*)wsb;                  wsb += (size_t)N_NODES * EMBED * 4;
    _Float16*  t16      = (_Float16*)wsb;               wsb += (size_t)N_NODES * EMBED * 2;
    __half*    hh       = (__half*)wsb;                 wsb += (size_t)N_NODES * EMBED * 2;
    _Float16*  wfrag    = (_Float16*)wsb;               wsb += (size_t)3 * 4096 * 2;
    unsigned*  binned   = (unsigned*)wsb;               wsb += (size_t)N_EDGES * 4;
    unsigned*  ebuf     = (unsigned*)wsb;               wsb += (size_t)N_EDGES * 4;
    int*       blockhist= (int*)wsb;                    wsb += (size_t)NBINS * NSCB * 4;
    int*       gofs     = (int*)wsb;                    wsb += (size_t)NBINS * NSCB * 4;
    int*       total    = (int*)wsb;                    wsb += (size_t)NBINS * 4;
    int*       binoff   = (int*)wsb;                    wsb += (size_t)(NBINS + 1) * 4;
    int*       rowptr   = (int*)wsb;                    wsb += (size_t)(N_NODES + 1) * 4;
    int*       gstart   = (int*)wsb;                    wsb += (size_t)(N_GRAPHS + 1) * 4;
    float*     Sbuf     = (float*)wsb;                  wsb += (size_t)3 * 4096 * 4;  // + mbuf adjacent
    float*     mbuf     = (float*)wsb;                  wsb += (size_t)3 * 64 * 4;
    float*     ssbuf    = (float*)wsb;                  wsb += (size_t)3 * 128 * 4;
    float*     gsum     = (float*)wsb;                  wsb += (size_t)N_GRAPHS * EMBED * 4;

    embed_kernel<<<(N_NODES * 16 + 255) / 256, 256, 0, stream>>>(
        nfeat, atom_embed, (float4*)h, hh, gid, gstart, gsum);
    hist2_kernel<<<NSCB, 256, 0, stream>>>(dst, blockhist);
    binreduce_kernel<<<NBINS, NSCB, 0, stream>>>(blockhist, gofs, total);
    binscan_kernel<<<1, 1024, 0, stream>>>(total, binoff, Sbuf, conv_W, wfrag);
    binscatter_kernel<<<NSCB, 256, 0, stream>>>(src, dst, efeat, binoff, gofs, binned);
    bincsr_kernel<<<NBINS, 256, 0, stream>>>(binned, binoff, rowptr, ebuf);

    for (int i = 0; i < 3; ++i) {
        gather_kernel<<<1536, 256, 0, stream>>>(
            rowptr, ebuf, bond_embed + i * 5 * EMBED, hh, h, (__half*)t16);
        float* Si = Sbuf + (size_t)i * 4096;
        float* mi = mbuf + (size_t)i * 64;
        float* ssi = ssbuf + (size_t)i * 128;
        gram_kernel<<<GRAM_BLOCKS, 256, 0, stream>>>((const _Float16*)t16, Si, mi);
        stats_kernel<<<1, 256, 0, stream>>>(
            Si, mi, conv_W + (size_t)i * 4096, conv_b + (size_t)i * EMBED,
            bn_gamma + (size_t)i * EMBED, bn_beta + (size_t)i * EMBED, ssi);
        const _Float16* wf = wfrag + (size_t)i * 4096;
        const float* bi = conv_b + (size_t)i * EMBED;
        if (i != 2) {
            gemm_bn2<<<GB_BLOCKS, 256, 0, stream>>>(
                (const _Float16*)t16, wf, bi, ssi, h, hh);
        } else {
            gemm_pool2<<<GB_BLOCKS, 256, 0, stream>>>(
                (const _Float16*)t16, wf, bi, ssi, h, gid, gsum);
        }
    }
    pred_kernel<<<N_GRAPHS, OUT_DIM, 0, stream>>>(gstart, gsum, pred_W, pred_b, out);
}

// Round 10
// 336.910 us; speedup vs baseline: 1.3442x; 1.2791x over previous
//
#include <hip/hip_runtime.h>
#include <hip/hip_fp16.h>

#define N_NODES 100000
#define N_EDGES 1000000
#define N_GRAPHS 1000
#define EMBED 64
#define OUT_DIM 128
#define BN_EPS 1e-5f
#define NBINS 782                          // dst>>7 -> 128 nodes per bin
#define NSCB 512                           // scatter blocks (fixed edge ranges)
#define EPB ((N_EDGES + NSCB - 1) / NSCB)  // 1954 edges per block
#define NTILES (N_NODES / 16)              // 6250 exact

#define GB_BLOCKS 512                      // fused gemm grid: 2 blocks/CU guaranteed resident
#define GB_WAVES (GB_BLOCKS * 4)           // 2048 waves
#define TPW 4                              // ceil(6250/2048) tiles per wave
#define BAR_STRIDE 8192                    // ints per barrier instance

typedef _Float16 half8 __attribute__((ext_vector_type(8)));
typedef float floatx4 __attribute__((ext_vector_type(4)));

// Software grid barrier v4 (graph-capture-safe). R6: barrier mechanics not the cost
// (v3==v4). R9: replacing barriers with analytic-BN recompute is WORSE (430 vs 337) —
// the ~19us/barrier is cheaper than any grid-wide recomputation. Keep v4; minimize count.
__device__ __forceinline__ void grid_barrier(int* p) {
    __syncthreads();
    if (threadIdx.x == 0) {
        asm volatile("" ::: "memory");
        int leaf = (int)blockIdx.x >> 3;
        int old = __hip_atomic_fetch_add(p + leaf * 32, 1,
                                         __ATOMIC_RELAXED, __HIP_MEMORY_SCOPE_AGENT);
        if (old == 7) {
            int r = __hip_atomic_fetch_add(p + 2048, 1,
                                           __ATOMIC_RELAXED, __HIP_MEMORY_SCOPE_AGENT);
            if (r == 63) {
                for (int g = 0; g < 64; ++g)
                    __hip_atomic_store(p + 2080 + g * 32, 1,
                                       __ATOMIC_RELAXED, __HIP_MEMORY_SCOPE_AGENT);
            }
        }
        int spins = 0;
        while (__hip_atomic_load(p + 2080 + leaf * 32,
                                 __ATOMIC_RELAXED, __HIP_MEMORY_SCOPE_AGENT) == 0) {
            __builtin_amdgcn_s_sleep(8);
            if (++spins > (1 << 17)) break;   // ~25ms failsafe: fail visibly, never wedge
        }
        asm volatile("" ::: "memory");
    }
    __syncthreads();
}

// ---------------- one-time structure kernels ----------------

__global__ void embed_kernel(const int* __restrict__ nfeat,
                             const float* __restrict__ atom_embed,
                             float4* __restrict__ h4,
                             __half* __restrict__ hh,
                             const int* __restrict__ gid,
                             int* __restrict__ gstart,
                             float* __restrict__ gsum) {
    int idx = blockIdx.x * blockDim.x + threadIdx.x;   // one float4 each
    if (idx <= N_NODES) {   // folded gbound
        int cur  = (idx < N_NODES) ? gid[idx] : N_GRAPHS;
        int prev = (idx == 0) ? -1 : gid[idx - 1];
        for (int g = prev + 1; g <= cur; ++g) gstart[g] = idx;
    }
    if (idx < N_GRAPHS * EMBED) gsum[idx] = 0.0f;
    if (idx >= N_NODES * 16) return;
    int v = idx >> 4, q = idx & 15;
    const float4* ae = (const float4*)atom_embed;
    float4 val = ae[nfeat[v] * 16 + q];
    h4[idx] = val;
    __half2 m0 = __floats2half2_rn(val.x, val.y);
    __half2 m1 = __floats2half2_rn(val.z, val.w);
    uint2 packed;
    packed.x = *(unsigned*)&m0;
    packed.y = *(unsigned*)&m1;
    ((uint2*)hh)[idx] = packed;
}

__global__ void hist2_kernel(const int* __restrict__ dst, int* __restrict__ blockhist) {
    __shared__ int hist[NBINS];
    for (int i = threadIdx.x; i < NBINS; i += 256) hist[i] = 0;
    __syncthreads();
    int b = blockIdx.x;
    int e0 = b * EPB, e1 = min(e0 + EPB, N_EDGES);
    for (int e = e0 + threadIdx.x; e < e1; e += 256)
        atomicAdd(&hist[dst[e] >> 7], 1);
    __syncthreads();
    for (int i = threadIdx.x; i < NBINS; i += 256)
        blockhist[i * NSCB + b] = hist[i];
}

__global__ void binreduce_kernel(const int* __restrict__ blockhist,
                                 int* __restrict__ gofs, int* __restrict__ total) {
    __shared__ int sm[NSCB];
    int bin = blockIdx.x;
    int i = threadIdx.x;   // 0..511
    int orig = blockhist[bin * NSCB + i];
    sm[i] = orig;
    __syncthreads();
    for (int off = 1; off < NSCB; off <<= 1) {
        int val = sm[i];
        if (i >= off) val += sm[i - off];
        __syncthreads();
        sm[i] = val;
        __syncthreads();
    }
    gofs[bin * NSCB + i] = sm[i] - orig;   // exclusive within bin
    if (i == NSCB - 1) total[bin] = sm[i];
}

__global__ void binscan_kernel(const int* __restrict__ total,
                               int* __restrict__ binoff, float* __restrict__ stats,
                               int* __restrict__ bar,
                               const float* __restrict__ conv_W,
                               _Float16* __restrict__ wfrag) {
    __shared__ int sm[1024];
    int i = threadIdx.x;
    if (i < 6 * EMBED) stats[i] = 0.0f;
    for (int s = i; s < 4 * BAR_STRIDE; s += 1024) bar[s] = 0;   // barrier instances
    // folded wpack: 3 layers x 512 slots
    for (int s = i; s < 3 * 512; s += 1024) {
        int L = s >> 9, slot = s & 511;
        int lane = slot & 63;
        int f = slot >> 6;          // nt*2+kh
        int nt = f >> 1, kh = f & 1;
        int n  = nt * 16 + (lane & 15);
        int k0 = kh * 32 + (lane >> 4) * 8;
        const float* W = conv_W + L * 4096;
        _Float16* out = wfrag + L * 4096;
#pragma unroll
        for (int j = 0; j < 8; ++j)
            out[slot * 8 + j] = (_Float16)W[(k0 + j) * 64 + n];
    }
    int orig = (i < NBINS) ? total[i] : 0;
    sm[i] = orig;
    __syncthreads();
    for (int off = 1; off < 1024; off <<= 1) {
        int val = sm[i];
        if (i >= off) val += sm[i - off];
        __syncthreads();
        sm[i] = val;
        __syncthreads();
    }
    if (i < NBINS) binoff[i] = sm[i] - orig;
    if (i == 0) binoff[NBINS] = N_EDGES;
}

__global__ void binscatter_kernel(const int* __restrict__ src, const int* __restrict__ dst,
                                  const int* __restrict__ efeat,
                                  const int* __restrict__ binoff, const int* __restrict__ gofs,
                                  unsigned* __restrict__ binned) {
    __shared__ int cur[NBINS];
    int b = blockIdx.x;
    for (int i = threadIdx.x; i < NBINS; i += 256)
        cur[i] = binoff[i] + gofs[i * NSCB + b];
    __syncthreads();
    int e0 = b * EPB, e1 = min(e0 + EPB, N_EDGES);
    for (int e = e0 + threadIdx.x; e < e1; e += 256) {
        int t = dst[e];
        int bin = t >> 7;
        int pos = atomicAdd(&cur[bin], 1);   // LDS atomic
        binned[pos] = (unsigned)src[e] | ((unsigned)efeat[e] << 17)
                    | ((unsigned)(t & 127) << 20);
    }
}

__global__ void bincsr_kernel(const unsigned* __restrict__ binned,
                              const int* __restrict__ binoff,
                              int* __restrict__ rowptr,
                              unsigned* __restrict__ ebuf) {
    __shared__ int cnt[128];
    __shared__ int sc[128];
    int b = blockIdx.x;
    int tid = threadIdx.x;
    int base = binoff[b], end = binoff[b + 1];

    if (tid < 128) cnt[tid] = 0;
    __syncthreads();

    for (int i = base + tid; i < end; i += 256)
        atomicAdd(&cnt[binned[i] >> 20], 1);
    __syncthreads();

    if (tid < 128) sc[tid] = cnt[tid];
    __syncthreads();
    for (int off = 1; off < 128; off <<= 1) {
        int val = 0;
        if (tid < 128) {
            val = sc[tid];
            if (tid >= off) val += sc[tid - off];
        }
        __syncthreads();
        if (tid < 128) sc[tid] = val;
        __syncthreads();
    }
    if (tid < 128) {
        int excl = sc[tid] - cnt[tid];
        int v = b * 128 + tid;
        if (v < N_NODES) rowptr[v] = base + excl;
        cnt[tid] = excl;   // becomes running cursor
    }
    if (b == 0 && tid == 255) rowptr[N_NODES] = N_EDGES;
    __syncthreads();

    for (int i = base + tid; i < end; i += 256) {
        unsigned rec = binned[i];
        int dl = rec >> 20;
        int pos = base + atomicAdd(&cnt[dl], 1);
        ebuf[pos] = (rec & 0x1FFFFu) | (((rec >> 17) & 0x7u) << 20);
    }
}

// ---------------- per-layer kernels ----------------

// Gather: quarter-wave per node. At the random-line service-rate wall (R6/R10/R18).
__launch_bounds__(256, 6)
__global__ void gather_kernel(const int* __restrict__ rowptr,
                              const unsigned* __restrict__ ebuf,
                              const float* __restrict__ bond,    // [5,64]
                              const __half* __restrict__ hh,     // fp16 mirror
                              const float* __restrict__ hmast,   // fp32 master
                              __half* __restrict__ t16) {
    __shared__ float bond_s[5 * EMBED];
    for (int i = threadIdx.x; i < 5 * EMBED; i += 256) bond_s[i] = bond[i];
    __syncthreads();

    int sl = threadIdx.x & 15;    // uint2 slot: dims 4sl..4sl+3
    int d0 = sl * 4;
    int gq = (blockIdx.x * 256 + threadIdx.x) >> 4;   // global quarter id
    int nq = (gridDim.x * 256) >> 4;
    const uint2* hhq = (const uint2*)hh;    // 16 uint2 per node row

    for (int v = gq; v < N_NODES; v += nq) {
        int rb = rowptr[v], re = rowptr[v + 1];
        float4 a0 = {0,0,0,0}, a1 = {0,0,0,0}, a2 = {0,0,0,0}, a3 = {0,0,0,0};
        int e = rb;
        for (; e + 4 <= re; e += 4) {
            unsigned p0 = ebuf[e + 0];
            unsigned p1 = ebuf[e + 1];
            unsigned p2 = ebuf[e + 2];
            unsigned p3 = ebuf[e + 3];
            uint2 g0 = hhq[(size_t)(p0 & 0xFFFFFu) * 16 + sl];
            uint2 g1 = hhq[(size_t)(p1 & 0xFFFFFu) * 16 + sl];
            uint2 g2 = hhq[(size_t)(p2 & 0xFFFFFu) * 16 + sl];
            uint2 g3 = hhq[(size_t)(p3 & 0xFFFFFu) * 16 + sl];
            const float* c0 = &bond_s[(p0 >> 20) * EMBED + d0];
            const float* c1 = &bond_s[(p1 >> 20) * EMBED + d0];
            const float* c2 = &bond_s[(p2 >> 20) * EMBED + d0];
            const float* c3 = &bond_s[(p3 >> 20) * EMBED + d0];
            float2 f0a = __half22float2(*(const __half2*)&g0.x);
            float2 f0b = __half22float2(*(const __half2*)&g0.y);
            float2 f1a = __half22float2(*(const __half2*)&g1.x);
            float2 f1b = __half22float2(*(const __half2*)&g1.y);
            float2 f2a = __half22float2(*(const __half2*)&g2.x);
            float2 f2b = __half22float2(*(const __half2*)&g2.y);
            float2 f3a = __half22float2(*(const __half2*)&g3.x);
            float2 f3b = __half22float2(*(const __half2*)&g3.y);
            a0.x += fmaxf(f0a.x + c0[0], 0.f); a0.y += fmaxf(f0a.y + c0[1], 0.f);
            a0.z += fmaxf(f0b.x + c0[2], 0.f); a0.w += fmaxf(f0b.y + c0[3], 0.f);
            a1.x += fmaxf(f1a.x + c1[0], 0.f); a1.y += fmaxf(f1a.y + c1[1], 0.f);
            a1.z += fmaxf(f1b.x + c1[2], 0.f); a1.w += fmaxf(f1b.y + c1[3], 0.f);
            a2.x += fmaxf(f2a.x + c2[0], 0.f); a2.y += fmaxf(f2a.y + c2[1], 0.f);
            a2.z += fmaxf(f2b.x + c2[2], 0.f); a2.w += fmaxf(f2b.y + c2[3], 0.f);
            a3.x += fmaxf(f3a.x + c3[0], 0.f); a3.y += fmaxf(f3a.y + c3[1], 0.f);
            a3.z += fmaxf(f3b.x + c3[2], 0.f); a3.w += fmaxf(f3b.y + c3[3], 0.f);
        }
        for (; e < re; ++e) {
            unsigned p = ebuf[e];
            uint2 g = hhq[(size_t)(p & 0xFFFFFu) * 16 + sl];
            const float* c = &bond_s[(p >> 20) * EMBED + d0];
            float2 fa = __half22float2(*(const __half2*)&g.x);
            float2 fb = __half22float2(*(const __half2*)&g.y);
            a0.x += fmaxf(fa.x + c[0], 0.f); a0.y += fmaxf(fa.y + c[1], 0.f);
            a0.z += fmaxf(fb.x + c[2], 0.f); a0.w += fmaxf(fb.y + c[3], 0.f);
        }
        float inv = 1.0f / fmaxf((float)(re - rb), 1.0f);
        float4 hr = ((const float4*)hmast)[(size_t)v * 16 + sl];
        float tx = (a0.x + a1.x + a2.x + a3.x) * inv + hr.x;
        float ty = (a0.y + a1.y + a2.y + a3.y) * inv + hr.y;
        float tz = (a0.z + a1.z + a2.z + a3.z) * inv + hr.z;
        float tw = (a0.w + a1.w + a2.w + a3.w) * inv + hr.w;
        __half2 m0 = __floats2half2_rn(tx, ty);
        __half2 m1 = __floats2half2_rn(tz, tw);
        uint2 packed;
        packed.x = *(unsigned*)&m0;
        packed.y = *(unsigned*)&m1;
        ((uint2*)t16)[(size_t)v * 16 + sl] = packed;
    }
}

// Fused GEMM + BN stats + grid barrier + BN/relu/residual (layers 0,1).
// MFMA accumulators stay in registers across the barrier: h_pre16 round-trip removed.
// C/D layout: col=lane&15, row=(lane>>4)*4+reg [m89].
__launch_bounds__(256, 2)
__global__ void gemm_bn_fused(const _Float16* __restrict__ t16,
                              const _Float16* __restrict__ wfrag,  // packed
                              const float* __restrict__ bias,
                              const float* __restrict__ gamma,
                              const float* __restrict__ beta,
                              float* __restrict__ colsum,
                              float* __restrict__ colsq,
                              int* __restrict__ bar,
                              float* __restrict__ h,      // fp32 master (in: residual, out: new h)
                              __half* __restrict__ hh) {  // fp16 mirror out
    __shared__ float red[4][8][16];
    __shared__ float sscale[EMBED];
    __shared__ float sshift[EMBED];

    int lane = threadIdx.x & 63;
    int wblk = threadIdx.x >> 6;
    int quad = lane >> 4;
    int col  = lane & 15;
    int wid  = blockIdx.x * 4 + wblk;

    half8 bf[4][2];
#pragma unroll
    for (int nt = 0; nt < 4; ++nt)
#pragma unroll
        for (int kh = 0; kh < 2; ++kh)
            bf[nt][kh] = *(const half8*)(wfrag + ((size_t)(nt * 2 + kh) * 64 + lane) * 8);

    float bj[4];
#pragma unroll
    for (int nt = 0; nt < 4; ++nt) bj[nt] = bias[nt * 16 + col];

    float lsum[4] = {0.f, 0.f, 0.f, 0.f};
    float lsq [4] = {0.f, 0.f, 0.f, 0.f};
    floatx4 c[TPW][4];

#pragma unroll
    for (int k = 0; k < TPW; ++k) {
        int tile = wid + k * GB_WAVES;
        if (tile >= NTILES) continue;
        int base = tile * 16;
        const _Float16* arow = t16 + (size_t)(base + col) * 64 + quad * 8;
        half8 a0 = *(const half8*)(arow);
        half8 a1 = *(const half8*)(arow + 32);
#pragma unroll
        for (int nt = 0; nt < 4; ++nt) {
            floatx4 cc = {bj[nt], bj[nt], bj[nt], bj[nt]};
            cc = __builtin_amdgcn_mfma_f32_16x16x32_f16(a0, bf[nt][0], cc, 0, 0, 0);
            cc = __builtin_amdgcn_mfma_f32_16x16x32_f16(a1, bf[nt][1], cc, 0, 0, 0);
            c[k][nt] = cc;
#pragma unroll
            for (int r = 0; r < 4; ++r) {
                float v = cc[r];
                lsum[nt] += v;
                lsq[nt]  += v * v;
            }
        }
    }

#pragma unroll
    for (int nt = 0; nt < 4; ++nt) {
        lsum[nt] += __shfl_xor(lsum[nt], 16); lsum[nt] += __shfl_xor(lsum[nt], 32);
        lsq[nt]  += __shfl_xor(lsq[nt], 16);  lsq[nt]  += __shfl_xor(lsq[nt], 32);
    }
    if (lane < 16) {
#pragma unroll
        for (int nt = 0; nt < 4; ++nt) {
            red[wblk][nt * 2 + 0][lane] = lsum[nt];
            red[wblk][nt * 2 + 1][lane] = lsq[nt];
        }
    }
    __syncthreads();
    if (threadIdx.x < 128) {
        int f = threadIdx.x >> 4, l = threadIdx.x & 15;
        float s = red[0][f][l] + red[1][f][l] + red[2][f][l] + red[3][f][l];
        int nt = f >> 1;
        if ((f & 1) == 0) atomicAdd(&colsum[nt * 16 + l], s);
        else              atomicAdd(&colsq[nt * 16 + l], s);
    }

    grid_barrier(bar);

    // stats -> scale/shift once per block (plain loads: L2-served broadcast)
    if (threadIdx.x < EMBED) {
        int j = threadIdx.x;
        const float invN = 1.0f / (float)N_NODES;
        float s = colsum[j];
        float q = colsq[j];
        float mu  = s * invN;
        float var = q * invN - mu * mu;
        float scv = rsqrtf(var + BN_EPS) * gamma[j];
        sscale[j] = scv;
        sshift[j] = beta[j] - mu * scv;
    }
    __syncthreads();

    float scr[4], shr[4];
#pragma unroll
    for (int nt = 0; nt < 4; ++nt) {
        scr[nt] = sscale[nt * 16 + col];
        shr[nt] = sshift[nt * 16 + col];
    }

#pragma unroll
    for (int k = 0; k < TPW; ++k) {
        int tile = wid + k * GB_WAVES;
        if (tile >= NTILES) continue;
        int base = tile * 16;
#pragma unroll
        for (int nt = 0; nt < 4; ++nt) {
#pragma unroll
            for (int r = 0; r < 4; ++r) {
                int node = base + quad * 4 + r;
                size_t off = (size_t)node * EMBED + nt * 16 + col;
                float y = fmaxf(c[k][nt][r] * scr[nt] + shr[nt], 0.0f);  // layers 0,1 relu
                float o = y + h[off];                                    // residual
                h[off] = o;
                hh[off] = __float2half(o);
            }
        }
    }
}

// Fused layer-2 GEMM + BN stats + barrier + BN/residual/graph-pool. R10: second
// barrier + pred phase removed — pred is a separate launch (kernel boundary = free
// grid barrier, ~4us vs ~19us software barrier).
__launch_bounds__(256, 2)
__global__ void gemm_pool_fused(const _Float16* __restrict__ t16,
                                const _Float16* __restrict__ wfrag,
                                const float* __restrict__ bias,
                                const float* __restrict__ gamma,
                                const float* __restrict__ beta,
                                float* __restrict__ colsum,
                                float* __restrict__ colsq,
                                int* __restrict__ bar,
                                const float* __restrict__ h, // residual (layer-1 output)
                                const int* __restrict__ gid,
                                float* __restrict__ gsum) {  // [N_GRAPHS, EMBED] zeroed
    __shared__ float red[4][8][16];
    __shared__ float sscale[EMBED];
    __shared__ float sshift[EMBED];

    int lane = threadIdx.x & 63;
    int wblk = threadIdx.x >> 6;
    int quad = lane >> 4;
    int col  = lane & 15;
    int wid  = blockIdx.x * 4 + wblk;

    half8 bf[4][2];
#pragma unroll
    for (int nt = 0; nt < 4; ++nt)
#pragma unroll
        for (int kh = 0; kh < 2; ++kh)
            bf[nt][kh] = *(const half8*)(wfrag + ((size_t)(nt * 2 + kh) * 64 + lane) * 8);

    float bj[4];
#pragma unroll
    for (int nt = 0; nt < 4; ++nt) bj[nt] = bias[nt * 16 + col];

    float lsum[4] = {0.f, 0.f, 0.f, 0.f};
    float lsq [4] = {0.f, 0.f, 0.f, 0.f};
    floatx4 c[TPW][4];

#pragma unroll
    for (int k = 0; k < TPW; ++k) {
        int tile = wid + k * GB_WAVES;
        if (tile >= NTILES) continue;
        int base = tile * 16;
        const _Float16* arow = t16 + (size_t)(base + col) * 64 + quad * 8;
        half8 a0 = *(const half8*)(arow);
        half8 a1 = *(const half8*)(arow + 32);
#pragma unroll
        for (int nt = 0; nt < 4; ++nt) {
            floatx4 cc = {bj[nt], bj[nt], bj[nt], bj[nt]};
            cc = __builtin_amdgcn_mfma_f32_16x16x32_f16(a0, bf[nt][0], cc, 0, 0, 0);
            cc = __builtin_amdgcn_mfma_f32_16x16x32_f16(a1, bf[nt][1], cc, 0, 0, 0);
            c[k][nt] = cc;
#pragma unroll
            for (int r = 0; r < 4; ++r) {
                float v = cc[r];
                lsum[nt] += v;
                lsq[nt]  += v * v;
            }
        }
    }

#pragma unroll
    for (int nt = 0; nt < 4; ++nt) {
        lsum[nt] += __shfl_xor(lsum[nt], 16); lsum[nt] += __shfl_xor(lsum[nt], 32);
        lsq[nt]  += __shfl_xor(lsq[nt], 16);  lsq[nt]  += __shfl_xor(lsq[nt], 32);
    }
    if (lane < 16) {
#pragma unroll
        for (int nt = 0; nt < 4; ++nt) {
            red[wblk][nt * 2 + 0][lane] = lsum[nt];
            red[wblk][nt * 2 + 1][lane] = lsq[nt];
        }
    }
    __syncthreads();
    if (threadIdx.x < 128) {
        int f = threadIdx.x >> 4, l = threadIdx.x & 15;
        float s = red[0][f][l] + red[1][f][l] + red[2][f][l] + red[3][f][l];
        int nt = f >> 1;
        if ((f & 1) == 0) atomicAdd(&colsum[nt * 16 + l], s);
        else              atomicAdd(&colsq[nt * 16 + l], s);
    }

    grid_barrier(bar);

    if (threadIdx.x < EMBED) {
        int j = threadIdx.x;
        const float invN = 1.0f / (float)N_NODES;
        float s = colsum[j];
        float q = colsq[j];
        float mu  = s * invN;
        float var = q * invN - mu * mu;
        float scv = rsqrtf(var + BN_EPS) * gamma[j];   // no relu on last layer
        sscale[j] = scv;
        sshift[j] = beta[j] - mu * scv;
    }
    __syncthreads();

    float scr[4], shr[4];
#pragma unroll
    for (int nt = 0; nt < 4; ++nt) {
        scr[nt] = sscale[nt * 16 + col];
        shr[nt] = sshift[nt * 16 + col];
    }

#pragma unroll
    for (int k = 0; k < TPW; ++k) {
        int tile = wid + k * GB_WAVES;
        if (tile >= NTILES) continue;
        int base = tile * 16;
        int g0  = gid[base];
        int g15 = gid[base + 15];
        float val[4][4];   // [nt][r]
#pragma unroll
        for (int r = 0; r < 4; ++r) {
            int node = base + quad * 4 + r;
#pragma unroll
            for (int nt = 0; nt < 4; ++nt) {
                size_t off = (size_t)node * EMBED + nt * 16 + col;
                val[nt][r] = c[k][nt][r] * scr[nt] + shr[nt] + h[off];
            }
        }
        if (g0 == g15) {   // gid sorted -> whole tile is one graph (wave-uniform branch)
#pragma unroll
            for (int nt = 0; nt < 4; ++nt) {
                float s = val[nt][0] + val[nt][1] + val[nt][2] + val[nt][3];
                s += __shfl_xor(s, 16);
                s += __shfl_xor(s, 32);
                if (quad == 0)
                    atomicAdd(&gsum[(size_t)g0 * EMBED + nt * 16 + col], s);
            }
        } else {
#pragma unroll
            for (int r = 0; r < 4; ++r) {
                int node = base + quad * 4 + r;
                int g = gid[node];
#pragma unroll
                for (int nt = 0; nt < 4; ++nt)
                    atomicAdd(&gsum[(size_t)g * EMBED + nt * 16 + col], val[nt][r]);
            }
        }
    }
}

// pred: block per graph; gm = gsum/cnt; out = gm @ predW + predb (verified R8/R9)
__global__ void pred_kernel(const int* __restrict__ gstart,
                            const float* __restrict__ gsum,
                            const float* __restrict__ predW,  // [64,128]
                            const float* __restrict__ predb,  // [128]
                            float* __restrict__ out) {        // [G,128]
    __shared__ float gm[EMBED];
    int g = blockIdx.x;
    if (threadIdx.x < EMBED) {
        int nb = gstart[g], ne = gstart[g + 1];
        gm[threadIdx.x] = gsum[(size_t)g * EMBED + threadIdx.x]
                        / fmaxf((float)(ne - nb), 1.0f);
    }
    __syncthreads();
    float acc = predb[threadIdx.x];
#pragma unroll
    for (int d = 0; d < EMBED; ++d)
        acc += gm[d] * predW[d * OUT_DIM + threadIdx.x];
    out[g * OUT_DIM + threadIdx.x] = acc;
}

// ---------------- launch ----------------

extern "C" void kernel_launch(void* const* d_in, const int* in_sizes, int n_in,
                              void* d_out, int out_size, void* d_ws, size_t ws_size,
                              hipStream_t stream) {
    const int*   nfeat      = (const int*)d_in[0];
    const int*   efeat      = (const int*)d_in[1];
    const int*   src        = (const int*)d_in[2];
    const int*   dst        = (const int*)d_in[3];
    const int*   gid        = (const int*)d_in[4];
    const float* atom_embed = (const float*)d_in[5];
    const float* bond_embed = (const float*)d_in[6];  // [3,5,64]
    const float* conv_W     = (const float*)d_in[7];  // [3,64,64]
    const float* conv_b     = (const float*)d_in[8];  // [3,64]
    const float* bn_gamma   = (const float*)d_in[9];  // [3,64]
    const float* bn_beta    = (const float*)d_in[10]; // [3,64]
    const float* pred_W     = (const float*)d_in[11]; // [64,128]
    const float* pred_b     = (const float*)d_in[12]; // [128]
    float* out = (float*)d_out;

    char* wsb = (char*)d_ws;
    float*     h        = (float*)wsb;                  wsb += (size_t)N_NODES * EMBED * 4;
    _Float16*  t16      = (_Float16*)wsb;               wsb += (size_t)N_NODES * EMBED * 2;
    __half*    hh       = (__half*)wsb;                 wsb += (size_t)N_NODES * EMBED * 2;
    _Float16*  wfrag    = (_Float16*)wsb;               wsb += (size_t)3 * 4096 * 2;
    unsigned*  binned   = (unsigned*)wsb;               wsb += (size_t)N_EDGES * 4;
    unsigned*  ebuf     = (unsigned*)wsb;               wsb += (size_t)N_EDGES * 4;
    int*       blockhist= (int*)wsb;                    wsb += (size_t)NBINS * NSCB * 4;
    int*       gofs     = (int*)wsb;                    wsb += (size_t)NBINS * NSCB * 4;
    int*       total    = (int*)wsb;                    wsb += (size_t)NBINS * 4;
    int*       binoff   = (int*)wsb;                    wsb += (size_t)(NBINS + 1) * 4;
    int*       rowptr   = (int*)wsb;                    wsb += (size_t)(N_NODES + 1) * 4;
    int*       gstart   = (int*)wsb;                    wsb += (size_t)(N_GRAPHS + 1) * 4;
    float*     colsum   = (float*)wsb;                  wsb += (size_t)3 * EMBED * 4;  // must stay
    float*     colsq    = (float*)wsb;                  wsb += (size_t)3 * EMBED * 4;  // adjacent
    float*     gsum     = (float*)wsb;                  wsb += (size_t)N_GRAPHS * EMBED * 4;
    int*       bar      = (int*)wsb;                    wsb += (size_t)4 * BAR_STRIDE * 4;

    embed_kernel<<<(N_NODES * 16 + 255) / 256, 256, 0, stream>>>(
        nfeat, atom_embed, (float4*)h, hh, gid, gstart, gsum);
    hist2_kernel<<<NSCB, 256, 0, stream>>>(dst, blockhist);
    binreduce_kernel<<<NBINS, NSCB, 0, stream>>>(blockhist, gofs, total);
    binscan_kernel<<<1, 1024, 0, stream>>>(total, binoff, colsum, bar, conv_W, wfrag);
    binscatter_kernel<<<NSCB, 256, 0, stream>>>(src, dst, efeat, binoff, gofs, binned);
    bincsr_kernel<<<NBINS, 256, 0, stream>>>(binned, binoff, rowptr, ebuf);

    for (int i = 0; i < 3; ++i) {
        gather_kernel<<<1536, 256, 0, stream>>>(
            rowptr, ebuf, bond_embed + i * 5 * EMBED, hh, h, (__half*)t16);
        const _Float16* wf = wfrag + (size_t)i * 4096;
        const float* bi = conv_b + (size_t)i * EMBED;
        const float* ga = bn_gamma + (size_t)i * EMBED;
        const float* be = bn_beta + (size_t)i * EMBED;
        float* cs = colsum + (size_t)i * EMBED;
        float* cq = colsq + (size_t)i * EMBED;
        if (i != 2) {
            gemm_bn_fused<<<GB_BLOCKS, 256, 0, stream>>>(
                t16, wf, bi, ga, be, cs, cq, bar + (size_t)i * BAR_STRIDE, h, hh);
        } else {
            gemm_pool_fused<<<GB_BLOCKS, 256, 0, stream>>>(
                t16, wf, bi, ga, be, cs, cq, bar + (size_t)2 * BAR_STRIDE,
                h, gid, gsum);
        }
    }
    pred_kernel<<<N_GRAPHS, OUT_DIM, 0, stream>>>(gstart, gsum, pred_W, pred_b, out);
}